// Round 16
// baseline (951.068 us; speedup 1.0000x reference)
//
#include <hip/hip_runtime.h>
#include <hip/hip_bf16.h>
#include <hip/hip_fp16.h>

#define BB 256
#define SS 32
#define II 128
#define HH 256
#define LBL 200
#define NSUBS 491
#define NATOMS_N 8000
#define NMOL_N 600

typedef const float* fp;
typedef __attribute__((ext_vector_type(8))) _Float16 f16x8;
typedef __attribute__((ext_vector_type(4))) float f32x4;

__device__ __forceinline__ float sigm(float x) { return 1.f / (1.f + expf(-x)); }
__device__ __forceinline__ float hlo(unsigned u) {
  return __half2float(__ushort_as_half((unsigned short)(u & 0xffffu)));
}
__device__ __forceinline__ float hhi(unsigned u) {
  return __half2float(__ushort_as_half((unsigned short)(u >> 16)));
}

// ---------------------------------------------------------------------------
// prep (1190 blocks): idxv, mstart, masked w_masklin, fp16 uint4-packed GRU
// weights wQ, and SPLIT-fp16 conversions of x and w_ih (hi + residual lo)
// so xp can be computed fp32-accurately on the matrix cores.
// ---------------------------------------------------------------------------
__global__ __launch_bounds__(256) void prep_kernel(
    const int* __restrict__ mask, int* __restrict__ idxv,
    const int* __restrict__ seg, int* __restrict__ mstart,
    fp w_masklin, fp ddi, float* __restrict__ mw,
    fp whh_c, fp whh_p, uint4* __restrict__ wQ,
    fp x_c, fp x_p, __half* __restrict__ xhi, __half* __restrict__ xlo,
    fp wih_c, fp wih_p, __half* __restrict__ whi, __half* __restrict__ wlo)
{
  int bx = blockIdx.x, tid = threadIdx.x;
  if (bx == 0) {                         // idx[b] = clamp(sum(mask[b,:]) - 1)
    int s = 0;
    const int* mrow = mask + tid * SS;
    for (int t = 0; t < SS; ++t) s += mrow[t];
    s -= 1;
    if (s < 0) s = 0;
    if (s > SS - 1) s = SS - 1;
    idxv[tid] = s;
  } else if (bx == 1) {                  // mstart[m] = lower_bound(seg, m)
    for (int m = tid; m <= NMOL_N; m += 256) {
      if (m == NMOL_N) { mstart[m] = NATOMS_N; continue; }
      int lo = 0, hi = NATOMS_N;
      while (lo < hi) {
        int mid = (lo + hi) >> 1;
        if (seg[mid] < m) lo = mid + 1; else hi = mid;
      }
      mstart[m] = lo;
    }
  } else if (bx < 6) {                   // mw[s][l] = w_masklin[s][l]*ddi[l][s]
    for (int o = (bx - 2) * 256 + tid; o < NSUBS * LBL; o += 4 * 256) {
      int s = o / LBL, l = o - s * LBL;
      mw[o] = w_masklin[o] * ddi[l * NSUBS + s];
    }
  } else if (bx < 70) {                  // weight pack: one (g, kk8) per block
    int lin = bx - 6;                    // 0..63
    int g = lin >> 5;
    int kk8 = lin & 31;
    fp whh = g ? whh_p : whh_c;
    uint4* dst = wQ + (size_t)(g * 32 + kk8) * 768;
#pragma unroll
    for (int gate = 0; gate < 3; ++gate) {
      const float* src = whh + (size_t)(gate * 256 + tid) * HH + kk8 * 8;
      unsigned v0 = __half_as_ushort(__float2half(src[0]));
      unsigned v1 = __half_as_ushort(__float2half(src[1]));
      unsigned v2 = __half_as_ushort(__float2half(src[2]));
      unsigned v3 = __half_as_ushort(__float2half(src[3]));
      unsigned v4 = __half_as_ushort(__float2half(src[4]));
      unsigned v5 = __half_as_ushort(__float2half(src[5]));
      unsigned v6 = __half_as_ushort(__float2half(src[6]));
      unsigned v7 = __half_as_ushort(__float2half(src[7]));
      uint4 u;
      u.x = v0 | (v1 << 16);
      u.y = v2 | (v3 << 16);
      u.z = v4 | (v5 << 16);
      u.w = v6 | (v7 << 16);
      dst[gate * 256 + tid] = u;
    }
  } else if (bx < 1094) {                // x -> fp16 hi+lo (2 x 1048576)
    int base = (bx - 70) * 2048;
    for (int o = base + tid; o < base + 2048; o += 256) {
      float v = (o < 1048576) ? x_c[o] : x_p[o - 1048576];
      __half h = __float2half(v);
      xhi[o] = h;
      xlo[o] = __float2half(v - __half2float(h));
    }
  } else {                               // w_ih -> fp16 hi+lo (2 x 98304)
    int base = (bx - 1094) * 2048;
    for (int o = base + tid; o < base + 2048; o += 256) {
      float v = (o < 98304) ? wih_c[o] : wih_p[o - 98304];
      __half h = __float2half(v);
      whi[o] = h;
      wlo[o] = __float2half(v - __half2float(h));
    }
  }
}

// ---------------------------------------------------------------------------
// xp = x @ w_ih.T + b_ih via SPLIT-fp16 MFMA (3 chains: hi*whi + lo*whi +
// hi*wlo; dropped lo*wlo term is O(1e-7) relative) -> fp32-accurate xp,
// stored fp32. One 16x16 tile per wave, K=128. grid (6144, 2) x 256.
// ---------------------------------------------------------------------------
__global__ __launch_bounds__(256) void xp_mfma(
    const __half* __restrict__ xhi, const __half* __restrict__ xlo,
    const __half* __restrict__ whi, const __half* __restrict__ wlo,
    fp bih_c, fp bih_p, float* __restrict__ xp)
{
  int g = blockIdx.y;
  const _Float16* xh = (const _Float16*)xhi + (size_t)g * 8192 * II;
  const _Float16* xl = (const _Float16*)xlo + (size_t)g * 8192 * II;
  const _Float16* wh = (const _Float16*)whi + (size_t)g * 768 * II;
  const _Float16* wl = (const _Float16*)wlo + (size_t)g * 768 * II;
  fp bih = g ? bih_p : bih_c;
  float* xpo = xp + (size_t)g * 8192 * 768;

  int wave = blockIdx.x * 4 + (threadIdx.x >> 6);
  int lane = threadIdx.x & 63;
  int mt = wave / 48, nt = wave - mt * 48;   // 512 x 48 tiles
  int m0 = mt << 4, n0 = nt << 4;
  int lm = lane & 15, q = lane >> 4;

  size_t aoff = (size_t)(m0 + lm) * II + q * 8;
  size_t boff = (size_t)(n0 + lm) * II + q * 8;
  const f16x8* ah = (const f16x8*)(xh + aoff);
  const f16x8* al = (const f16x8*)(xl + aoff);
  const f16x8* bh = (const f16x8*)(wh + boff);
  const f16x8* bl = (const f16x8*)(wl + boff);
  f32x4 acc = {0.f, 0.f, 0.f, 0.f};
#pragma unroll
  for (int kk = 0; kk < 4; ++kk) {
    f16x8 a = ah[kk * 4], b = bh[kk * 4];
    acc = __builtin_amdgcn_mfma_f32_16x16x32_f16(a, b, acc, 0, 0, 0);
    acc = __builtin_amdgcn_mfma_f32_16x16x32_f16(al[kk * 4], b, acc, 0, 0, 0);
    acc = __builtin_amdgcn_mfma_f32_16x16x32_f16(a, bl[kk * 4], acc, 0, 0, 0);
  }
  float bias = bih[n0 + lm];
#pragma unroll
  for (int r = 0; r < 4; ++r)
    xpo[(size_t)(m0 + q * 4 + r) * 768 + n0 + lm] = acc[r] + bias;
}

// ---------------------------------------------------------------------------
// fully-fused MPNN: one block per molecule (<=14 atoms).
// ---------------------------------------------------------------------------
__global__ __launch_bounds__(256) void mpnn_mol(
    const int* __restrict__ fingerprints, fp embed_fp, fp adj,
    const int* __restrict__ mstart, fp w_g0, fp b_g0, fp w_g1, fp b_g1,
    float* __restrict__ mol)
{
  int m = blockIdx.x, tid = threadIdx.x;
  int a0 = mstart[m], a1 = mstart[m + 1];
  int sz = a1 - a0;
  if (sz < 0) sz = 0;
  if (sz > 14) sz = 14;

  __shared__ float v[14][260];
  __shared__ float adjb[14][16];

#pragma unroll
  for (int i = 0; i < 14; ++i) {
    float val = 0.f;
    if (i < sz) {
      int f = fingerprints[a0 + i] & 1023;
      val = embed_fp[(size_t)f * HH + tid];
    }
    v[i][tid] = val;
  }
  if (tid < 224) {
    int i = tid >> 4, jj = tid & 15;
    float a = 0.f;
    if (i < sz && jj < sz)
      a = adj[(size_t)(a0 + i) * NATOMS_N + a0 + jj];
    adjb[i][jj] = a;
  }
  __syncthreads();

  float acc[14];
  for (int rd = 0; rd < 2; ++rd) {
    const float* wp0 = (rd ? w_g1 : w_g0) + tid;
#pragma unroll
    for (int i = 0; i < 14; ++i) acc[i] = 0.f;
    for (int k = 0; k < HH; k += 4) {
      float w0 = wp0[(size_t)k * HH];
      float w1 = wp0[(size_t)(k + 1) * HH];
      float w2 = wp0[(size_t)(k + 2) * HH];
      float w3 = wp0[(size_t)(k + 3) * HH];
#pragma unroll
      for (int i = 0; i < 14; ++i) {
        float4 vv = *(const float4*)&v[i][k];
        acc[i] = fmaf(vv.x, w0, acc[i]);
        acc[i] = fmaf(vv.y, w1, acc[i]);
        acc[i] = fmaf(vv.z, w2, acc[i]);
        acc[i] = fmaf(vv.w, w3, acc[i]);
      }
    }
    float bias = (rd ? b_g1 : b_g0)[tid];
    float hreg[14];
#pragma unroll
    for (int i = 0; i < 14; ++i) hreg[i] = fmaxf(acc[i] + bias, 0.f);
#pragma unroll
    for (int i = 0; i < 14; ++i) {
      float s = hreg[i];
#pragma unroll
      for (int jj = 0; jj < 14; ++jj) s = fmaf(adjb[i][jj], hreg[jj], s);
      acc[i] = s;
    }
    if (rd == 0) {
      __syncthreads();
#pragma unroll
      for (int i = 0; i < 14; ++i) v[i][tid] = acc[i];
      __syncthreads();
    }
  }
  float msum = 0.f;
#pragma unroll
  for (int i = 0; i < 14; ++i) if (i < sz) msum += acc[i];
  mol[(size_t)m * HH + tid] = msum;
}

// ---------------------------------------------------------------------------
// mpnn_emb^T[h][d] = sum_m avg[d][m] * mol[m][h]
// ---------------------------------------------------------------------------
__global__ __launch_bounds__(256) void mpnn_emb_k(
    fp avg, const float* __restrict__ mol, float* __restrict__ embT)
{
  int d = blockIdx.x, tid = threadIdx.x;
  float acc = 0.f;
  for (int m = 0; m < NMOL_N; ++m)
    acc += avg[d * NMOL_N + m] * mol[(size_t)m * HH + tid];
  embT[(size_t)tid * LBL + d] = acc;
}

// ---------------------------------------------------------------------------
// GRU v4 (round-13 proven): k-split, 256 blocks (g x 128 pairs) x 512 thr.
// fp32 h in LDS; fp16 uint4 weights streamed from XCD-L2; partials via LDS.
// ---------------------------------------------------------------------------
__global__ __launch_bounds__(512) void gru_ks(
    fp xp, const uint4* __restrict__ wQ, fp bhh_c, fp bhh_p,
    float* __restrict__ hcat, const int* __restrict__ idxv)
{
  int blk = blockIdx.x;
  int g = blk >> 7;
  int pair = blk & 127;
  int b1 = pair * 2, b2 = b1 + 1;
  int tid = threadIdx.x;
  int j = tid & 255;
  int kh = tid >> 8;                   // k-half 0/1

  __shared__ float hs[2][260];         // [batch][k]
  __shared__ float red[12][260];       // [kh*6 + batch*3 + gate][j]

  const uint4* wg = wQ + (size_t)(g * 32 + kh * 16) * 768 + j;
  fp bhh = g ? bhh_p : bhh_c;
  const float* xpg = xp + (size_t)g * 8192 * 768;

  if (kh == 0) { hs[0][j] = 0.f; hs[1][j] = 0.f; }
  float br = bhh[j], bz = bhh[j + 256], bn = bhh[j + 512];
  int myb = kh ? b2 : b1;
  int myid = idxv[myb];
  __syncthreads();

  for (int t = 0; t < SS; ++t) {
    const float* h1p = &hs[0][kh * 128];
    const float* h2p = &hs[1][kh * 128];
    float s1r = 0.f, s1z = 0.f, s1n = 0.f;
    float s2r = 0.f, s2z = 0.f, s2n = 0.f;
#pragma unroll 4
    for (int i = 0; i < 16; ++i) {
      float4 a1a = *(const float4*)(h1p + i * 8);
      float4 a1b = *(const float4*)(h1p + i * 8 + 4);
      float4 a2a = *(const float4*)(h2p + i * 8);
      float4 a2b = *(const float4*)(h2p + i * 8 + 4);
      const uint4* base = wg + (size_t)i * 768;
      uint4 ur = base[0];
      uint4 uz = base[256];
      uint4 un = base[512];
      // gate r
      {
        float w0 = hlo(ur.x), w1 = hhi(ur.x), w2 = hlo(ur.y), w3 = hhi(ur.y);
        float w4 = hlo(ur.z), w5 = hhi(ur.z), w6 = hlo(ur.w), w7 = hhi(ur.w);
        s1r = fmaf(a1a.x, w0, s1r); s1r = fmaf(a1a.y, w1, s1r);
        s1r = fmaf(a1a.z, w2, s1r); s1r = fmaf(a1a.w, w3, s1r);
        s1r = fmaf(a1b.x, w4, s1r); s1r = fmaf(a1b.y, w5, s1r);
        s1r = fmaf(a1b.z, w6, s1r); s1r = fmaf(a1b.w, w7, s1r);
        s2r = fmaf(a2a.x, w0, s2r); s2r = fmaf(a2a.y, w1, s2r);
        s2r = fmaf(a2a.z, w2, s2r); s2r = fmaf(a2a.w, w3, s2r);
        s2r = fmaf(a2b.x, w4, s2r); s2r = fmaf(a2b.y, w5, s2r);
        s2r = fmaf(a2b.z, w6, s2r); s2r = fmaf(a2b.w, w7, s2r);
      }
      // gate z
      {
        float w0 = hlo(uz.x), w1 = hhi(uz.x), w2 = hlo(uz.y), w3 = hhi(uz.y);
        float w4 = hlo(uz.z), w5 = hhi(uz.z), w6 = hlo(uz.w), w7 = hhi(uz.w);
        s1z = fmaf(a1a.x, w0, s1z); s1z = fmaf(a1a.y, w1, s1z);
        s1z = fmaf(a1a.z, w2, s1z); s1z = fmaf(a1a.w, w3, s1z);
        s1z = fmaf(a1b.x, w4, s1z); s1z = fmaf(a1b.y, w5, s1z);
        s1z = fmaf(a1b.z, w6, s1z); s1z = fmaf(a1b.w, w7, s1z);
        s2z = fmaf(a2a.x, w0, s2z); s2z = fmaf(a2a.y, w1, s2z);
        s2z = fmaf(a2a.z, w2, s2z); s2z = fmaf(a2a.w, w3, s2z);
        s2z = fmaf(a2b.x, w4, s2z); s2z = fmaf(a2b.y, w5, s2z);
        s2z = fmaf(a2b.z, w6, s2z); s2z = fmaf(a2b.w, w7, s2z);
      }
      // gate n
      {
        float w0 = hlo(un.x), w1 = hhi(un.x), w2 = hlo(un.y), w3 = hhi(un.y);
        float w4 = hlo(un.z), w5 = hhi(un.z), w6 = hlo(un.w), w7 = hhi(un.w);
        s1n = fmaf(a1a.x, w0, s1n); s1n = fmaf(a1a.y, w1, s1n);
        s1n = fmaf(a1a.z, w2, s1n); s1n = fmaf(a1a.w, w3, s1n);
        s1n = fmaf(a1b.x, w4, s1n); s1n = fmaf(a1b.y, w5, s1n);
        s1n = fmaf(a1b.z, w6, s1n); s1n = fmaf(a1b.w, w7, s1n);
        s2n = fmaf(a2a.x, w0, s2n); s2n = fmaf(a2a.y, w1, s2n);
        s2n = fmaf(a2a.z, w2, s2n); s2n = fmaf(a2a.w, w3, s2n);
        s2n = fmaf(a2b.x, w4, s2n); s2n = fmaf(a2b.y, w5, s2n);
        s2n = fmaf(a2b.z, w6, s2n); s2n = fmaf(a2b.w, w7, s2n);
      }
    }
    int rb = kh * 6;
    red[rb + 0][j] = s1r; red[rb + 1][j] = s1z; red[rb + 2][j] = s1n;
    red[rb + 3][j] = s2r; red[rb + 4][j] = s2z; red[rb + 5][j] = s2n;
    __syncthreads();                   // partials visible; all hs reads done

    // gate phase: thread (kh = batch-in-pair, j); writes only its own hs slot
    {
      int bb = kh * 3;
      float sr = red[bb + 0][j] + red[6 + bb + 0][j];
      float sz = red[bb + 1][j] + red[6 + bb + 1][j];
      float sn = red[bb + 2][j] + red[6 + bb + 2][j];
      const float* xrow = xpg + ((size_t)myb * SS + t) * 768;
      float r = sigm(xrow[j] + sr + br);
      float z = sigm(xrow[j + 256] + sz + bz);
      float n = tanhf(xrow[j + 512] + r * (sn + bn));
      float hnew = (1.f - z) * n + z * hs[kh][j];
      hs[kh][j] = hnew;
      if (t == myid) hcat[(size_t)myb * 512 + g * 256 + j] = fmaxf(hnew, 0.f);
    }
    __syncthreads();                   // hs update visible before next step
  }
}

// ---------------------------------------------------------------------------
// fp32 GEMM for query: C[M,N] = A[M,K] @ W[K,N] + bias
// ---------------------------------------------------------------------------
__global__ __launch_bounds__(256) void gemm_f32(
    const float* __restrict__ A, fp W, fp bias, float* __restrict__ C,
    int M, int N, int K)
{
  int ntiles = N >> 4;
  int mt = blockIdx.x / ntiles, nt = blockIdx.x - mt * ntiles;
  int m0 = mt << 4, n0 = nt << 4;
  int tid = threadIdx.x;
  int ni = tid & 15, mi = tid >> 4;
  __shared__ float As[16][68];
  float acc = 0.f;
  for (int k0 = 0; k0 < K; k0 += 64) {
    __syncthreads();
    for (int i = tid; i < 1024; i += 256) {
      int r = i >> 6, kk = i & 63;
      As[r][kk] = A[(size_t)(m0 + r) * K + k0 + kk];
    }
    __syncthreads();
    const float* wp = W + (size_t)k0 * N + n0 + ni;
#pragma unroll 4
    for (int kk = 0; kk < 64; ++kk)
      acc = fmaf(As[mi][kk], wp[(size_t)kk * N], acc);
  }
  acc += bias[n0 + ni];
  C[(size_t)(m0 + mi) * N + n0 + ni] = acc;
}

// ---------------------------------------------------------------------------
// fused tail per batch row: match/x2/LN (mpnn_att) + bip/masked-linear + mul
// ---------------------------------------------------------------------------
__global__ __launch_bounds__(256) void tail_fused(
    const float* __restrict__ query, const float* __restrict__ embT,
    fp w_out, fp b_out, fp gamma, fp beta,
    fp w_bip, fp b_bip, const float* __restrict__ mw,
    float* __restrict__ out)
{
  int b = blockIdx.x, tid = threadIdx.x;
  __shared__ float q[HH];
  __shared__ float mrow[LBL];
  __shared__ float bips[NSUBS];
  __shared__ float red[256];
  q[tid] = query[(size_t)b * HH + tid];
  __syncthreads();
  if (tid < LBL) {
    float acc = 0.f;
    for (int k = 0; k < HH; ++k) acc += q[k] * embT[(size_t)k * LBL + tid];
    mrow[tid] = sigm(acc);
  }
  for (int s = tid; s < NSUBS; s += 256) {
    float acc = b_bip[s];
    for (int k = 0; k < HH; ++k) acc += q[k] * w_bip[(size_t)k * NSUBS + s];
    bips[s] = acc;
  }
  __syncthreads();
  float x2 = 0.f;
  if (tid < LBL) {
    float acc = b_out[tid] + mrow[tid];
    for (int jj = 0; jj < LBL; ++jj) acc += mrow[jj] * w_out[jj * LBL + tid];
    x2 = acc;
  }
  red[tid] = (tid < LBL) ? x2 : 0.f;
  __syncthreads();
  for (int s = 128; s > 0; s >>= 1) {
    if (tid < s) red[tid] += red[tid + s];
    __syncthreads();
  }
  float mu = red[0] / (float)LBL;
  __syncthreads();
  float dv = (tid < LBL) ? (x2 - mu) : 0.f;
  red[tid] = dv * dv;
  __syncthreads();
  for (int s = 128; s > 0; s >>= 1) {
    if (tid < s) red[tid] += red[tid + s];
    __syncthreads();
  }
  float var = red[0] / (float)LBL;
  if (tid < LBL) {
    float matt = (x2 - mu) * rsqrtf(var + 1e-5f) * gamma[tid] + beta[tid];
    float acc = 0.f;
    for (int s = 0; s < NSUBS; ++s) acc += bips[s] * mw[(size_t)s * LBL + tid];
    out[(size_t)b * LBL + tid] = acc * matt;
  }
}

// ---------------------------------------------------------------------------
extern "C" void kernel_launch(void* const* d_in, const int* in_sizes, int n_in,
                              void* d_out, int out_size, void* d_ws, size_t ws_size,
                              hipStream_t stream)
{
  fp x_c   = (fp)d_in[0];
  fp x_p   = (fp)d_in[1];
  const int* mask = (const int*)d_in[2];
  fp wih_c = (fp)d_in[3];
  fp whh_c = (fp)d_in[4];
  fp bih_c = (fp)d_in[5];
  fp bhh_c = (fp)d_in[6];
  fp wih_p = (fp)d_in[7];
  fp whh_p = (fp)d_in[8];
  fp bih_p = (fp)d_in[9];
  fp bhh_p = (fp)d_in[10];
  fp w_query = (fp)d_in[11];
  fp b_query = (fp)d_in[12];
  fp w_bip = (fp)d_in[13];
  fp b_bip = (fp)d_in[14];
  fp w_masklin = (fp)d_in[15];
  fp ddi = (fp)d_in[16];
  fp embed_fp = (fp)d_in[17];
  const int* fingerprints = (const int*)d_in[18];
  fp adj = (fp)d_in[19];
  const int* seg = (const int*)d_in[20];
  fp w_g0 = (fp)d_in[21];
  fp b_g0 = (fp)d_in[22];
  fp w_g1 = (fp)d_in[23];
  fp b_g1 = (fp)d_in[24];
  fp avg = (fp)d_in[25];
  fp w_out = (fp)d_in[26];
  fp b_out = (fp)d_in[27];
  fp gamma = (fp)d_in[28];
  fp beta = (fp)d_in[29];
  float* out = (float*)d_out;

  char* w = (char*)d_ws;
  size_t off = 0;
  auto alloc = [&](size_t bytes) -> void* {
    void* p = w + off;
    off = (off + bytes + 255) & ~(size_t)255;
    return p;
  };

  float* xp   = (float*)alloc((size_t)2 * 8192 * 768 * 4);    // 50.3 MB
  __half* xhi = (__half*)alloc((size_t)2 * 8192 * 128 * 2);   // 4.2 MB
  __half* xlo = (__half*)alloc((size_t)2 * 8192 * 128 * 2);   // 4.2 MB
  __half* whi = (__half*)alloc((size_t)2 * 768 * 128 * 2);    // 0.4 MB
  __half* wlo = (__half*)alloc((size_t)2 * 768 * 128 * 2);    // 0.4 MB
  uint4* wQ   = (uint4*)alloc((size_t)2 * 32 * 768 * 16);     // 786 KB
  float* mol  = (float*)alloc((size_t)NMOL_N * HH * 4);
  float* embT = (float*)alloc((size_t)HH * LBL * 4);
  float* hcat = (float*)alloc((size_t)BB * 2 * HH * 4);
  float* query = (float*)alloc((size_t)BB * HH * 4);
  float* mw   = (float*)alloc((size_t)NSUBS * LBL * 4);
  int* idxv   = (int*)alloc(256 * 4);
  int* mstart = (int*)alloc((NMOL_N + 1) * 4);

  prep_kernel<<<1190, 256, 0, stream>>>(mask, idxv, seg, mstart, w_masklin,
                                        ddi, mw, whh_c, whh_p, wQ,
                                        x_c, x_p, xhi, xlo,
                                        wih_c, wih_p, whi, wlo);

  xp_mfma<<<dim3(6144, 2), 256, 0, stream>>>(xhi, xlo, whi, wlo,
                                             bih_c, bih_p, xp);

  mpnn_mol<<<NMOL_N, 256, 0, stream>>>(fingerprints, embed_fp, adj, mstart,
                                       w_g0, b_g0, w_g1, b_g1, mol);
  mpnn_emb_k<<<LBL, 256, 0, stream>>>(avg, mol, embT);

  gru_ks<<<256, 512, 0, stream>>>(xp, wQ, bhh_c, bhh_p, hcat, idxv);

  gemm_f32<<<256, 256, 0, stream>>>(hcat, w_query, b_query, query, BB, HH, 2 * HH);
  tail_fused<<<BB, 256, 0, stream>>>(query, embT, w_out, b_out, gamma, beta,
                                     w_bip, b_bip, mw, out);
}

// Round 17
// 848.621 us; speedup vs baseline: 1.1207x; 1.1207x over previous
//
#include <hip/hip_runtime.h>
#include <hip/hip_bf16.h>
#include <hip/hip_fp16.h>

#define BB 256
#define SS 32
#define II 128
#define HH 256
#define LBL 200
#define NSUBS 491
#define NATOMS_N 8000
#define NMOL_N 600

typedef const float* fp;
typedef __attribute__((ext_vector_type(2))) _Float16 h2t;
typedef __attribute__((ext_vector_type(8))) _Float16 f16x8;
typedef __attribute__((ext_vector_type(4))) float f32x4;

__device__ __forceinline__ float sigm(float x) { return 1.f / (1.f + expf(-x)); }
__device__ __forceinline__ float hlo(unsigned u) {
  return __half2float(__ushort_as_half((unsigned short)(u & 0xffffu)));
}
__device__ __forceinline__ float hhi(unsigned u) {
  return __half2float(__ushort_as_half((unsigned short)(u >> 16)));
}

#if __has_builtin(__builtin_amdgcn_fdot2)
__device__ __forceinline__ float dot2u(unsigned ha, unsigned wa, float acc) {
  return __builtin_amdgcn_fdot2(__builtin_bit_cast(h2t, ha),
                                __builtin_bit_cast(h2t, wa), acc, false);
}
#else
__device__ __forceinline__ float dot2u(unsigned ha, unsigned wa, float acc) {
  acc = fmaf(hlo(ha), hlo(wa), acc);
  return fmaf(hhi(ha), hhi(wa), acc);
}
#endif

// ---------------------------------------------------------------------------
// prep (1190 blocks): idxv, mstart, masked w_masklin, fp16 uint4-packed GRU
// weights wQ, and SPLIT-fp16 conversions of x and w_ih (hi + residual lo)
// so xp can be computed fp32-accurately on the matrix cores.
// ---------------------------------------------------------------------------
__global__ __launch_bounds__(256) void prep_kernel(
    const int* __restrict__ mask, int* __restrict__ idxv,
    const int* __restrict__ seg, int* __restrict__ mstart,
    fp w_masklin, fp ddi, float* __restrict__ mw,
    fp whh_c, fp whh_p, uint4* __restrict__ wQ,
    fp x_c, fp x_p, __half* __restrict__ xhi, __half* __restrict__ xlo,
    fp wih_c, fp wih_p, __half* __restrict__ whi, __half* __restrict__ wlo)
{
  int bx = blockIdx.x, tid = threadIdx.x;
  if (bx == 0) {                         // idx[b] = clamp(sum(mask[b,:]) - 1)
    int s = 0;
    const int* mrow = mask + tid * SS;
    for (int t = 0; t < SS; ++t) s += mrow[t];
    s -= 1;
    if (s < 0) s = 0;
    if (s > SS - 1) s = SS - 1;
    idxv[tid] = s;
  } else if (bx == 1) {                  // mstart[m] = lower_bound(seg, m)
    for (int m = tid; m <= NMOL_N; m += 256) {
      if (m == NMOL_N) { mstart[m] = NATOMS_N; continue; }
      int lo = 0, hi = NATOMS_N;
      while (lo < hi) {
        int mid = (lo + hi) >> 1;
        if (seg[mid] < m) lo = mid + 1; else hi = mid;
      }
      mstart[m] = lo;
    }
  } else if (bx < 6) {                   // mw[s][l] = w_masklin[s][l]*ddi[l][s]
    for (int o = (bx - 2) * 256 + tid; o < NSUBS * LBL; o += 4 * 256) {
      int s = o / LBL, l = o - s * LBL;
      mw[o] = w_masklin[o] * ddi[l * NSUBS + s];
    }
  } else if (bx < 70) {                  // weight pack: one (g, kk8) per block
    int lin = bx - 6;                    // 0..63
    int g = lin >> 5;
    int kk8 = lin & 31;
    fp whh = g ? whh_p : whh_c;
    uint4* dst = wQ + (size_t)(g * 32 + kk8) * 768;
#pragma unroll
    for (int gate = 0; gate < 3; ++gate) {
      const float* src = whh + (size_t)(gate * 256 + tid) * HH + kk8 * 8;
      unsigned v0 = __half_as_ushort(__float2half(src[0]));
      unsigned v1 = __half_as_ushort(__float2half(src[1]));
      unsigned v2 = __half_as_ushort(__float2half(src[2]));
      unsigned v3 = __half_as_ushort(__float2half(src[3]));
      unsigned v4 = __half_as_ushort(__float2half(src[4]));
      unsigned v5 = __half_as_ushort(__float2half(src[5]));
      unsigned v6 = __half_as_ushort(__float2half(src[6]));
      unsigned v7 = __half_as_ushort(__float2half(src[7]));
      uint4 u;
      u.x = v0 | (v1 << 16);
      u.y = v2 | (v3 << 16);
      u.z = v4 | (v5 << 16);
      u.w = v6 | (v7 << 16);
      dst[gate * 256 + tid] = u;
    }
  } else if (bx < 1094) {                // x -> fp16 hi+lo (2 x 1048576)
    int base = (bx - 70) * 2048;
    for (int o = base + tid; o < base + 2048; o += 256) {
      float v = (o < 1048576) ? x_c[o] : x_p[o - 1048576];
      __half h = __float2half(v);
      xhi[o] = h;
      xlo[o] = __float2half(v - __half2float(h));
    }
  } else {                               // w_ih -> fp16 hi+lo (2 x 98304)
    int base = (bx - 1094) * 2048;
    for (int o = base + tid; o < base + 2048; o += 256) {
      float v = (o < 98304) ? wih_c[o] : wih_p[o - 98304];
      __half h = __float2half(v);
      whi[o] = h;
      wlo[o] = __float2half(v - __half2float(h));
    }
  }
}

// ---------------------------------------------------------------------------
// xp = x @ w_ih.T + b_ih via SPLIT-fp16 MFMA (3 chains: hi*whi + lo*whi +
// hi*wlo) -> fp32-accurate xp, stored fp32. grid (6144, 2) x 256.
// ---------------------------------------------------------------------------
__global__ __launch_bounds__(256) void xp_mfma(
    const __half* __restrict__ xhi, const __half* __restrict__ xlo,
    const __half* __restrict__ whi, const __half* __restrict__ wlo,
    fp bih_c, fp bih_p, float* __restrict__ xp)
{
  int g = blockIdx.y;
  const _Float16* xh = (const _Float16*)xhi + (size_t)g * 8192 * II;
  const _Float16* xl = (const _Float16*)xlo + (size_t)g * 8192 * II;
  const _Float16* wh = (const _Float16*)whi + (size_t)g * 768 * II;
  const _Float16* wl = (const _Float16*)wlo + (size_t)g * 768 * II;
  fp bih = g ? bih_p : bih_c;
  float* xpo = xp + (size_t)g * 8192 * 768;

  int wave = blockIdx.x * 4 + (threadIdx.x >> 6);
  int lane = threadIdx.x & 63;
  int mt = wave / 48, nt = wave - mt * 48;   // 512 x 48 tiles
  int m0 = mt << 4, n0 = nt << 4;
  int lm = lane & 15, q = lane >> 4;

  size_t aoff = (size_t)(m0 + lm) * II + q * 8;
  size_t boff = (size_t)(n0 + lm) * II + q * 8;
  const f16x8* ah = (const f16x8*)(xh + aoff);
  const f16x8* al = (const f16x8*)(xl + aoff);
  const f16x8* bh = (const f16x8*)(wh + boff);
  const f16x8* bl = (const f16x8*)(wl + boff);
  f32x4 acc = {0.f, 0.f, 0.f, 0.f};
#pragma unroll
  for (int kk = 0; kk < 4; ++kk) {
    f16x8 a = ah[kk * 4], b = bh[kk * 4];
    acc = __builtin_amdgcn_mfma_f32_16x16x32_f16(a, b, acc, 0, 0, 0);
    acc = __builtin_amdgcn_mfma_f32_16x16x32_f16(al[kk * 4], b, acc, 0, 0, 0);
    acc = __builtin_amdgcn_mfma_f32_16x16x32_f16(a, bl[kk * 4], acc, 0, 0, 0);
  }
  float bias = bih[n0 + lm];
#pragma unroll
  for (int r = 0; r < 4; ++r)
    xpo[(size_t)(m0 + q * 4 + r) * 768 + n0 + lm] = acc[r] + bias;
}

// ---------------------------------------------------------------------------
// fully-fused MPNN: one block per molecule (<=14 atoms).
// ---------------------------------------------------------------------------
__global__ __launch_bounds__(256) void mpnn_mol(
    const int* __restrict__ fingerprints, fp embed_fp, fp adj,
    const int* __restrict__ mstart, fp w_g0, fp b_g0, fp w_g1, fp b_g1,
    float* __restrict__ mol)
{
  int m = blockIdx.x, tid = threadIdx.x;
  int a0 = mstart[m], a1 = mstart[m + 1];
  int sz = a1 - a0;
  if (sz < 0) sz = 0;
  if (sz > 14) sz = 14;

  __shared__ float v[14][260];
  __shared__ float adjb[14][16];

#pragma unroll
  for (int i = 0; i < 14; ++i) {
    float val = 0.f;
    if (i < sz) {
      int f = fingerprints[a0 + i] & 1023;
      val = embed_fp[(size_t)f * HH + tid];
    }
    v[i][tid] = val;
  }
  if (tid < 224) {
    int i = tid >> 4, jj = tid & 15;
    float a = 0.f;
    if (i < sz && jj < sz)
      a = adj[(size_t)(a0 + i) * NATOMS_N + a0 + jj];
    adjb[i][jj] = a;
  }
  __syncthreads();

  float acc[14];
  for (int rd = 0; rd < 2; ++rd) {
    const float* wp0 = (rd ? w_g1 : w_g0) + tid;
#pragma unroll
    for (int i = 0; i < 14; ++i) acc[i] = 0.f;
    for (int k = 0; k < HH; k += 4) {
      float w0 = wp0[(size_t)k * HH];
      float w1 = wp0[(size_t)(k + 1) * HH];
      float w2 = wp0[(size_t)(k + 2) * HH];
      float w3 = wp0[(size_t)(k + 3) * HH];
#pragma unroll
      for (int i = 0; i < 14; ++i) {
        float4 vv = *(const float4*)&v[i][k];
        acc[i] = fmaf(vv.x, w0, acc[i]);
        acc[i] = fmaf(vv.y, w1, acc[i]);
        acc[i] = fmaf(vv.z, w2, acc[i]);
        acc[i] = fmaf(vv.w, w3, acc[i]);
      }
    }
    float bias = (rd ? b_g1 : b_g0)[tid];
    float hreg[14];
#pragma unroll
    for (int i = 0; i < 14; ++i) hreg[i] = fmaxf(acc[i] + bias, 0.f);
#pragma unroll
    for (int i = 0; i < 14; ++i) {
      float s = hreg[i];
#pragma unroll
      for (int jj = 0; jj < 14; ++jj) s = fmaf(adjb[i][jj], hreg[jj], s);
      acc[i] = s;
    }
    if (rd == 0) {
      __syncthreads();
#pragma unroll
      for (int i = 0; i < 14; ++i) v[i][tid] = acc[i];
      __syncthreads();
    }
  }
  float msum = 0.f;
#pragma unroll
  for (int i = 0; i < 14; ++i) if (i < sz) msum += acc[i];
  mol[(size_t)m * HH + tid] = msum;
}

// ---------------------------------------------------------------------------
// mpnn_emb^T[h][d] = sum_m avg[d][m] * mol[m][h]
// ---------------------------------------------------------------------------
__global__ __launch_bounds__(256) void mpnn_emb_k(
    fp avg, const float* __restrict__ mol, float* __restrict__ embT)
{
  int d = blockIdx.x, tid = threadIdx.x;
  float acc = 0.f;
  for (int m = 0; m < NMOL_N; ++m)
    acc += avg[d * NMOL_N + m] * mol[(size_t)m * HH + tid];
  embT[(size_t)tid * LBL + d] = acc;
}

// ---------------------------------------------------------------------------
// GRU v6 (dot2): r13/r16 skeleton — fp32 h state, fp32 gate phase — plus a
// packed-fp16 mirror hsh of h used only as dot-loop input. hsh is written
// with 4-byte uint stores (pack phase, threads 0..255) and read as 16B
// uint4 — NO sub-dword LDS writes (the r14 suspect). 3 syncs/step.
// 256 blocks (g x 128 pairs) x 512 threads.
// ---------------------------------------------------------------------------
__global__ __launch_bounds__(512) void gru_dot(
    fp xp, const uint4* __restrict__ wQ, fp bhh_c, fp bhh_p,
    float* __restrict__ hcat, const int* __restrict__ idxv)
{
  int blk = blockIdx.x;
  int g = blk >> 7;
  int pair = blk & 127;
  int b1 = pair * 2, b2 = b1 + 1;
  int tid = threadIdx.x;
  int j = tid & 255;
  int kh = tid >> 8;                   // k-half 0/1

  __shared__ float hs[2][260];         // [batch][k]   fp32 state (proven)
  __shared__ unsigned hsh[2][132];     // [batch][k/2] packed fp16 mirror
  __shared__ float red[12][260];       // [kh*6 + batch*3 + gate][j]

  const uint4* wg = wQ + (size_t)(g * 32 + kh * 16) * 768 + j;
  fp bhh = g ? bhh_p : bhh_c;
  const float* xpg = xp + (size_t)g * 8192 * 768;

  if (kh == 0) { hs[0][j] = 0.f; hs[1][j] = 0.f; }
  if (tid < 128) hsh[0][tid] = 0u;
  else if (tid < 256) hsh[1][tid - 128] = 0u;
  float br = bhh[j], bz = bhh[j + 256], bn = bhh[j + 512];
  int myb = kh ? b2 : b1;
  int myid = idxv[myb];
  __syncthreads();

  for (int t = 0; t < SS; ++t) {
    // dot phase: packed fp16 h (uint4 = 8 k-values) x packed fp16 weights
    const uint4* h1p = (const uint4*)&hsh[0][kh * 64];
    const uint4* h2p = (const uint4*)&hsh[1][kh * 64];
    float s1r = 0.f, s1z = 0.f, s1n = 0.f;
    float s2r = 0.f, s2z = 0.f, s2n = 0.f;
#pragma unroll 4
    for (int i = 0; i < 16; ++i) {
      uint4 H1 = h1p[i];
      uint4 H2 = h2p[i];
      const uint4* base = wg + (size_t)i * 768;
      uint4 ur = base[0];
      uint4 uz = base[256];
      uint4 un = base[512];
      s1r = dot2u(H1.x, ur.x, s1r); s1r = dot2u(H1.y, ur.y, s1r);
      s1r = dot2u(H1.z, ur.z, s1r); s1r = dot2u(H1.w, ur.w, s1r);
      s1z = dot2u(H1.x, uz.x, s1z); s1z = dot2u(H1.y, uz.y, s1z);
      s1z = dot2u(H1.z, uz.z, s1z); s1z = dot2u(H1.w, uz.w, s1z);
      s1n = dot2u(H1.x, un.x, s1n); s1n = dot2u(H1.y, un.y, s1n);
      s1n = dot2u(H1.z, un.z, s1n); s1n = dot2u(H1.w, un.w, s1n);
      s2r = dot2u(H2.x, ur.x, s2r); s2r = dot2u(H2.y, ur.y, s2r);
      s2r = dot2u(H2.z, ur.z, s2r); s2r = dot2u(H2.w, ur.w, s2r);
      s2z = dot2u(H2.x, uz.x, s2z); s2z = dot2u(H2.y, uz.y, s2z);
      s2z = dot2u(H2.z, uz.z, s2z); s2z = dot2u(H2.w, uz.w, s2z);
      s2n = dot2u(H2.x, un.x, s2n); s2n = dot2u(H2.y, un.y, s2n);
      s2n = dot2u(H2.z, un.z, s2n); s2n = dot2u(H2.w, un.w, s2n);
    }
    int rb = kh * 6;
    red[rb + 0][j] = s1r; red[rb + 1][j] = s1z; red[rb + 2][j] = s1n;
    red[rb + 3][j] = s2r; red[rb + 4][j] = s2z; red[rb + 5][j] = s2n;
    __syncthreads();                   // partials visible; all hsh reads done

    // gate phase: thread (kh = batch-in-pair, j); fp32, writes own hs slot
    {
      int bb = kh * 3;
      float sr = red[bb + 0][j] + red[6 + bb + 0][j];
      float sz = red[bb + 1][j] + red[6 + bb + 1][j];
      float sn = red[bb + 2][j] + red[6 + bb + 2][j];
      const float* xrow = xpg + ((size_t)myb * SS + t) * 768;
      float r = sigm(xrow[j] + sr + br);
      float z = sigm(xrow[j + 256] + sz + bz);
      float n = tanhf(xrow[j + 512] + r * (sn + bn));
      float hnew = (1.f - z) * n + z * hs[kh][j];
      hs[kh][j] = hnew;
      if (t == myid) hcat[(size_t)myb * 512 + g * 256 + j] = fmaxf(hnew, 0.f);
    }
    __syncthreads();                   // hs update visible to pack phase

    // pack phase: 4-byte uint stores of fp16 pairs (no sub-dword writes)
    if (tid < 128) {
      unsigned lo16 = __half_as_ushort(__float2half(hs[0][2 * tid]));
      unsigned hi16 = __half_as_ushort(__float2half(hs[0][2 * tid + 1]));
      hsh[0][tid] = lo16 | (hi16 << 16);
    } else if (tid < 256) {
      int p = tid - 128;
      unsigned lo16 = __half_as_ushort(__float2half(hs[1][2 * p]));
      unsigned hi16 = __half_as_ushort(__float2half(hs[1][2 * p + 1]));
      hsh[1][p] = lo16 | (hi16 << 16);
    }
    __syncthreads();                   // hsh visible before next dot phase
  }
}

// ---------------------------------------------------------------------------
// fp32 GEMM for query: C[M,N] = A[M,K] @ W[K,N] + bias
// ---------------------------------------------------------------------------
__global__ __launch_bounds__(256) void gemm_f32(
    const float* __restrict__ A, fp W, fp bias, float* __restrict__ C,
    int M, int N, int K)
{
  int ntiles = N >> 4;
  int mt = blockIdx.x / ntiles, nt = blockIdx.x - mt * ntiles;
  int m0 = mt << 4, n0 = nt << 4;
  int tid = threadIdx.x;
  int ni = tid & 15, mi = tid >> 4;
  __shared__ float As[16][68];
  float acc = 0.f;
  for (int k0 = 0; k0 < K; k0 += 64) {
    __syncthreads();
    for (int i = tid; i < 1024; i += 256) {
      int r = i >> 6, kk = i & 63;
      As[r][kk] = A[(size_t)(m0 + r) * K + k0 + kk];
    }
    __syncthreads();
    const float* wp = W + (size_t)k0 * N + n0 + ni;
#pragma unroll 4
    for (int kk = 0; kk < 64; ++kk)
      acc = fmaf(As[mi][kk], wp[(size_t)kk * N], acc);
  }
  acc += bias[n0 + ni];
  C[(size_t)(m0 + mi) * N + n0 + ni] = acc;
}

// ---------------------------------------------------------------------------
// fused tail per batch row: match/x2/LN (mpnn_att) + bip/masked-linear + mul
// ---------------------------------------------------------------------------
__global__ __launch_bounds__(256) void tail_fused(
    const float* __restrict__ query, const float* __restrict__ embT,
    fp w_out, fp b_out, fp gamma, fp beta,
    fp w_bip, fp b_bip, const float* __restrict__ mw,
    float* __restrict__ out)
{
  int b = blockIdx.x, tid = threadIdx.x;
  __shared__ float q[HH];
  __shared__ float mrow[LBL];
  __shared__ float bips[NSUBS];
  __shared__ float red[256];
  q[tid] = query[(size_t)b * HH + tid];
  __syncthreads();
  if (tid < LBL) {
    float acc = 0.f;
    for (int k = 0; k < HH; ++k) acc += q[k] * embT[(size_t)k * LBL + tid];
    mrow[tid] = sigm(acc);
  }
  for (int s = tid; s < NSUBS; s += 256) {
    float acc = b_bip[s];
    for (int k = 0; k < HH; ++k) acc += q[k] * w_bip[(size_t)k * NSUBS + s];
    bips[s] = acc;
  }
  __syncthreads();
  float x2 = 0.f;
  if (tid < LBL) {
    float acc = b_out[tid] + mrow[tid];
    for (int jj = 0; jj < LBL; ++jj) acc += mrow[jj] * w_out[jj * LBL + tid];
    x2 = acc;
  }
  red[tid] = (tid < LBL) ? x2 : 0.f;
  __syncthreads();
  for (int s = 128; s > 0; s >>= 1) {
    if (tid < s) red[tid] += red[tid + s];
    __syncthreads();
  }
  float mu = red[0] / (float)LBL;
  __syncthreads();
  float dv = (tid < LBL) ? (x2 - mu) : 0.f;
  red[tid] = dv * dv;
  __syncthreads();
  for (int s = 128; s > 0; s >>= 1) {
    if (tid < s) red[tid] += red[tid + s];
    __syncthreads();
  }
  float var = red[0] / (float)LBL;
  if (tid < LBL) {
    float matt = (x2 - mu) * rsqrtf(var + 1e-5f) * gamma[tid] + beta[tid];
    float acc = 0.f;
    for (int s = 0; s < NSUBS; ++s) acc += bips[s] * mw[(size_t)s * LBL + tid];
    out[(size_t)b * LBL + tid] = acc * matt;
  }
}

// ---------------------------------------------------------------------------
extern "C" void kernel_launch(void* const* d_in, const int* in_sizes, int n_in,
                              void* d_out, int out_size, void* d_ws, size_t ws_size,
                              hipStream_t stream)
{
  fp x_c   = (fp)d_in[0];
  fp x_p   = (fp)d_in[1];
  const int* mask = (const int*)d_in[2];
  fp wih_c = (fp)d_in[3];
  fp whh_c = (fp)d_in[4];
  fp bih_c = (fp)d_in[5];
  fp bhh_c = (fp)d_in[6];
  fp wih_p = (fp)d_in[7];
  fp whh_p = (fp)d_in[8];
  fp bih_p = (fp)d_in[9];
  fp bhh_p = (fp)d_in[10];
  fp w_query = (fp)d_in[11];
  fp b_query = (fp)d_in[12];
  fp w_bip = (fp)d_in[13];
  fp b_bip = (fp)d_in[14];
  fp w_masklin = (fp)d_in[15];
  fp ddi = (fp)d_in[16];
  fp embed_fp = (fp)d_in[17];
  const int* fingerprints = (const int*)d_in[18];
  fp adj = (fp)d_in[19];
  const int* seg = (const int*)d_in[20];
  fp w_g0 = (fp)d_in[21];
  fp b_g0 = (fp)d_in[22];
  fp w_g1 = (fp)d_in[23];
  fp b_g1 = (fp)d_in[24];
  fp avg = (fp)d_in[25];
  fp w_out = (fp)d_in[26];
  fp b_out = (fp)d_in[27];
  fp gamma = (fp)d_in[28];
  fp beta = (fp)d_in[29];
  float* out = (float*)d_out;

  char* w = (char*)d_ws;
  size_t off = 0;
  auto alloc = [&](size_t bytes) -> void* {
    void* p = w + off;
    off = (off + bytes + 255) & ~(size_t)255;
    return p;
  };

  float* xp   = (float*)alloc((size_t)2 * 8192 * 768 * 4);    // 50.3 MB
  __half* xhi = (__half*)alloc((size_t)2 * 8192 * 128 * 2);   // 4.2 MB
  __half* xlo = (__half*)alloc((size_t)2 * 8192 * 128 * 2);   // 4.2 MB
  __half* whi = (__half*)alloc((size_t)2 * 768 * 128 * 2);    // 0.4 MB
  __half* wlo = (__half*)alloc((size_t)2 * 768 * 128 * 2);    // 0.4 MB
  uint4* wQ   = (uint4*)alloc((size_t)2 * 32 * 768 * 16);     // 786 KB
  float* mol  = (float*)alloc((size_t)NMOL_N * HH * 4);
  float* embT = (float*)alloc((size_t)HH * LBL * 4);
  float* hcat = (float*)alloc((size_t)BB * 2 * HH * 4);
  float* query = (float*)alloc((size_t)BB * HH * 4);
  float* mw   = (float*)alloc((size_t)NSUBS * LBL * 4);
  int* idxv   = (int*)alloc(256 * 4);
  int* mstart = (int*)alloc((NMOL_N + 1) * 4);

  prep_kernel<<<1190, 256, 0, stream>>>(mask, idxv, seg, mstart, w_masklin,
                                        ddi, mw, whh_c, whh_p, wQ,
                                        x_c, x_p, xhi, xlo,
                                        wih_c, wih_p, whi, wlo);

  xp_mfma<<<dim3(6144, 2), 256, 0, stream>>>(xhi, xlo, whi, wlo,
                                             bih_c, bih_p, xp);

  mpnn_mol<<<NMOL_N, 256, 0, stream>>>(fingerprints, embed_fp, adj, mstart,
                                       w_g0, b_g0, w_g1, b_g1, mol);
  mpnn_emb_k<<<LBL, 256, 0, stream>>>(avg, mol, embT);

  gru_dot<<<256, 512, 0, stream>>>(xp, wQ, bhh_c, bhh_p, hcat, idxv);

  gemm_f32<<<256, 256, 0, stream>>>(hcat, w_query, b_query, query, BB, HH, 2 * HH);
  tail_fused<<<BB, 256, 0, stream>>>(query, embT, w_out, b_out, gamma, beta,
                                     w_bip, b_bip, mw, out);
}

// Round 18
// 810.134 us; speedup vs baseline: 1.1740x; 1.0475x over previous
//
#include <hip/hip_runtime.h>
#include <hip/hip_bf16.h>
#include <hip/hip_fp16.h>

#define BB 256
#define SS 32
#define II 128
#define HH 256
#define LBL 200
#define NSUBS 491
#define NATOMS_N 8000
#define NMOL_N 600

typedef const float* fp;
typedef __attribute__((ext_vector_type(2))) _Float16 h2t;
typedef __attribute__((ext_vector_type(8))) _Float16 f16x8;
typedef __attribute__((ext_vector_type(4))) float f32x4;

__device__ __forceinline__ float sigm(float x) { return 1.f / (1.f + expf(-x)); }
__device__ __forceinline__ float hlo(unsigned u) {
  return __half2float(__ushort_as_half((unsigned short)(u & 0xffffu)));
}
__device__ __forceinline__ float hhi(unsigned u) {
  return __half2float(__ushort_as_half((unsigned short)(u >> 16)));
}

#if __has_builtin(__builtin_amdgcn_fdot2)
__device__ __forceinline__ float dot2u(unsigned ha, unsigned wa, float acc) {
  return __builtin_amdgcn_fdot2(__builtin_bit_cast(h2t, ha),
                                __builtin_bit_cast(h2t, wa), acc, false);
}
#else
__device__ __forceinline__ float dot2u(unsigned ha, unsigned wa, float acc) {
  acc = fmaf(hlo(ha), hlo(wa), acc);
  return fmaf(hhi(ha), hhi(wa), acc);
}
#endif

// ---------------------------------------------------------------------------
// prep (1190 blocks): idxv, mstart, masked w_masklin, fp16 uint4-packed GRU
// weights wQ, and SPLIT-fp16 conversions of x and w_ih (hi + residual lo)
// so xp can be computed fp32-accurately on the matrix cores.
// ---------------------------------------------------------------------------
__global__ __launch_bounds__(256) void prep_kernel(
    const int* __restrict__ mask, int* __restrict__ idxv,
    const int* __restrict__ seg, int* __restrict__ mstart,
    fp w_masklin, fp ddi, float* __restrict__ mw,
    fp whh_c, fp whh_p, uint4* __restrict__ wQ,
    fp x_c, fp x_p, __half* __restrict__ xhi, __half* __restrict__ xlo,
    fp wih_c, fp wih_p, __half* __restrict__ whi, __half* __restrict__ wlo)
{
  int bx = blockIdx.x, tid = threadIdx.x;
  if (bx == 0) {                         // idx[b] = clamp(sum(mask[b,:]) - 1)
    int s = 0;
    const int* mrow = mask + tid * SS;
    for (int t = 0; t < SS; ++t) s += mrow[t];
    s -= 1;
    if (s < 0) s = 0;
    if (s > SS - 1) s = SS - 1;
    idxv[tid] = s;
  } else if (bx == 1) {                  // mstart[m] = lower_bound(seg, m)
    for (int m = tid; m <= NMOL_N; m += 256) {
      if (m == NMOL_N) { mstart[m] = NATOMS_N; continue; }
      int lo = 0, hi = NATOMS_N;
      while (lo < hi) {
        int mid = (lo + hi) >> 1;
        if (seg[mid] < m) lo = mid + 1; else hi = mid;
      }
      mstart[m] = lo;
    }
  } else if (bx < 6) {                   // mw[s][l] = w_masklin[s][l]*ddi[l][s]
    for (int o = (bx - 2) * 256 + tid; o < NSUBS * LBL; o += 4 * 256) {
      int s = o / LBL, l = o - s * LBL;
      mw[o] = w_masklin[o] * ddi[l * NSUBS + s];
    }
  } else if (bx < 70) {                  // weight pack: one (g, kk8) per block
    int lin = bx - 6;                    // 0..63
    int g = lin >> 5;
    int kk8 = lin & 31;
    fp whh = g ? whh_p : whh_c;
    uint4* dst = wQ + (size_t)(g * 32 + kk8) * 768;
#pragma unroll
    for (int gate = 0; gate < 3; ++gate) {
      const float* src = whh + (size_t)(gate * 256 + tid) * HH + kk8 * 8;
      unsigned v0 = __half_as_ushort(__float2half(src[0]));
      unsigned v1 = __half_as_ushort(__float2half(src[1]));
      unsigned v2 = __half_as_ushort(__float2half(src[2]));
      unsigned v3 = __half_as_ushort(__float2half(src[3]));
      unsigned v4 = __half_as_ushort(__float2half(src[4]));
      unsigned v5 = __half_as_ushort(__float2half(src[5]));
      unsigned v6 = __half_as_ushort(__float2half(src[6]));
      unsigned v7 = __half_as_ushort(__float2half(src[7]));
      uint4 u;
      u.x = v0 | (v1 << 16);
      u.y = v2 | (v3 << 16);
      u.z = v4 | (v5 << 16);
      u.w = v6 | (v7 << 16);
      dst[gate * 256 + tid] = u;
    }
  } else if (bx < 1094) {                // x -> fp16 hi+lo (2 x 1048576)
    int base = (bx - 70) * 2048;
    for (int o = base + tid; o < base + 2048; o += 256) {
      float v = (o < 1048576) ? x_c[o] : x_p[o - 1048576];
      __half h = __float2half(v);
      xhi[o] = h;
      xlo[o] = __float2half(v - __half2float(h));
    }
  } else {                               // w_ih -> fp16 hi+lo (2 x 98304)
    int base = (bx - 1094) * 2048;
    for (int o = base + tid; o < base + 2048; o += 256) {
      float v = (o < 98304) ? wih_c[o] : wih_p[o - 98304];
      __half h = __float2half(v);
      whi[o] = h;
      wlo[o] = __float2half(v - __half2float(h));
    }
  }
}

// ---------------------------------------------------------------------------
// xp = x @ w_ih.T + b_ih via SPLIT-fp16 MFMA (3 chains: hi*whi + lo*whi +
// hi*wlo) -> fp32-accurate xp, stored fp32. grid (6144, 2) x 256.
// ---------------------------------------------------------------------------
__global__ __launch_bounds__(256) void xp_mfma(
    const __half* __restrict__ xhi, const __half* __restrict__ xlo,
    const __half* __restrict__ whi, const __half* __restrict__ wlo,
    fp bih_c, fp bih_p, float* __restrict__ xp)
{
  int g = blockIdx.y;
  const _Float16* xh = (const _Float16*)xhi + (size_t)g * 8192 * II;
  const _Float16* xl = (const _Float16*)xlo + (size_t)g * 8192 * II;
  const _Float16* wh = (const _Float16*)whi + (size_t)g * 768 * II;
  const _Float16* wl = (const _Float16*)wlo + (size_t)g * 768 * II;
  fp bih = g ? bih_p : bih_c;
  float* xpo = xp + (size_t)g * 8192 * 768;

  int wave = blockIdx.x * 4 + (threadIdx.x >> 6);
  int lane = threadIdx.x & 63;
  int mt = wave / 48, nt = wave - mt * 48;   // 512 x 48 tiles
  int m0 = mt << 4, n0 = nt << 4;
  int lm = lane & 15, q = lane >> 4;

  size_t aoff = (size_t)(m0 + lm) * II + q * 8;
  size_t boff = (size_t)(n0 + lm) * II + q * 8;
  const f16x8* ah = (const f16x8*)(xh + aoff);
  const f16x8* al = (const f16x8*)(xl + aoff);
  const f16x8* bh = (const f16x8*)(wh + boff);
  const f16x8* bl = (const f16x8*)(wl + boff);
  f32x4 acc = {0.f, 0.f, 0.f, 0.f};
#pragma unroll
  for (int kk = 0; kk < 4; ++kk) {
    f16x8 a = ah[kk * 4], b = bh[kk * 4];
    acc = __builtin_amdgcn_mfma_f32_16x16x32_f16(a, b, acc, 0, 0, 0);
    acc = __builtin_amdgcn_mfma_f32_16x16x32_f16(al[kk * 4], b, acc, 0, 0, 0);
    acc = __builtin_amdgcn_mfma_f32_16x16x32_f16(a, bl[kk * 4], acc, 0, 0, 0);
  }
  float bias = bih[n0 + lm];
#pragma unroll
  for (int r = 0; r < 4; ++r)
    xpo[(size_t)(m0 + q * 4 + r) * 768 + n0 + lm] = acc[r] + bias;
}

// ---------------------------------------------------------------------------
// fully-fused MPNN: one block per molecule (<=14 atoms).
// ---------------------------------------------------------------------------
__global__ __launch_bounds__(256) void mpnn_mol(
    const int* __restrict__ fingerprints, fp embed_fp, fp adj,
    const int* __restrict__ mstart, fp w_g0, fp b_g0, fp w_g1, fp b_g1,
    float* __restrict__ mol)
{
  int m = blockIdx.x, tid = threadIdx.x;
  int a0 = mstart[m], a1 = mstart[m + 1];
  int sz = a1 - a0;
  if (sz < 0) sz = 0;
  if (sz > 14) sz = 14;

  __shared__ float v[14][260];
  __shared__ float adjb[14][16];

#pragma unroll
  for (int i = 0; i < 14; ++i) {
    float val = 0.f;
    if (i < sz) {
      int f = fingerprints[a0 + i] & 1023;
      val = embed_fp[(size_t)f * HH + tid];
    }
    v[i][tid] = val;
  }
  if (tid < 224) {
    int i = tid >> 4, jj = tid & 15;
    float a = 0.f;
    if (i < sz && jj < sz)
      a = adj[(size_t)(a0 + i) * NATOMS_N + a0 + jj];
    adjb[i][jj] = a;
  }
  __syncthreads();

  float acc[14];
  for (int rd = 0; rd < 2; ++rd) {
    const float* wp0 = (rd ? w_g1 : w_g0) + tid;
#pragma unroll
    for (int i = 0; i < 14; ++i) acc[i] = 0.f;
    for (int k = 0; k < HH; k += 4) {
      float w0 = wp0[(size_t)k * HH];
      float w1 = wp0[(size_t)(k + 1) * HH];
      float w2 = wp0[(size_t)(k + 2) * HH];
      float w3 = wp0[(size_t)(k + 3) * HH];
#pragma unroll
      for (int i = 0; i < 14; ++i) {
        float4 vv = *(const float4*)&v[i][k];
        acc[i] = fmaf(vv.x, w0, acc[i]);
        acc[i] = fmaf(vv.y, w1, acc[i]);
        acc[i] = fmaf(vv.z, w2, acc[i]);
        acc[i] = fmaf(vv.w, w3, acc[i]);
      }
    }
    float bias = (rd ? b_g1 : b_g0)[tid];
    float hreg[14];
#pragma unroll
    for (int i = 0; i < 14; ++i) hreg[i] = fmaxf(acc[i] + bias, 0.f);
#pragma unroll
    for (int i = 0; i < 14; ++i) {
      float s = hreg[i];
#pragma unroll
      for (int jj = 0; jj < 14; ++jj) s = fmaf(adjb[i][jj], hreg[jj], s);
      acc[i] = s;
    }
    if (rd == 0) {
      __syncthreads();
#pragma unroll
      for (int i = 0; i < 14; ++i) v[i][tid] = acc[i];
      __syncthreads();
    }
  }
  float msum = 0.f;
#pragma unroll
  for (int i = 0; i < 14; ++i) if (i < sz) msum += acc[i];
  mol[(size_t)m * HH + tid] = msum;
}

// ---------------------------------------------------------------------------
// mpnn_emb^T[h][d] = sum_m avg[d][m] * mol[m][h]
// ---------------------------------------------------------------------------
__global__ __launch_bounds__(256) void mpnn_emb_k(
    fp avg, const float* __restrict__ mol, float* __restrict__ embT)
{
  int d = blockIdx.x, tid = threadIdx.x;
  float acc = 0.f;
  for (int m = 0; m < NMOL_N; ++m)
    acc += avg[d * NMOL_N + m] * mol[(size_t)m * HH + tid];
  embT[(size_t)tid * LBL + d] = acc;
}

// ---------------------------------------------------------------------------
// GRU v7 (dot2, k-split 4): 256 blocks (g x 128 pairs) x 1024 threads ->
// 16 waves/CU (4/SIMD) hide L2 weight-load latency; per-CU load count and
// bytes UNCHANGED vs r17 (each thread 24 uint4 instead of 48 — the r13
// lesson: more waves only wins if loads don't grow). Same race-proof LDS
// discipline: fp32 h state, packed-fp16 mirror via 4-byte stores only.
// ---------------------------------------------------------------------------
__global__ __launch_bounds__(1024) void gru_dot4(
    fp xp, const uint4* __restrict__ wQ, fp bhh_c, fp bhh_p,
    float* __restrict__ hcat, const int* __restrict__ idxv)
{
  int blk = blockIdx.x;
  int g = blk >> 7;
  int pair = blk & 127;
  int b1 = pair * 2, b2 = b1 + 1;
  int tid = threadIdx.x;
  int j = tid & 255;
  int kq = tid >> 8;                   // k-quarter 0..3

  __shared__ float hs[2][260];         // [batch][k]   fp32 state (proven)
  __shared__ unsigned hsh[2][132];     // [batch][k/2] packed fp16 mirror
  __shared__ float red[24][260];       // [kq*6 + batch*3 + gate][j]

  const uint4* wg = wQ + (size_t)(g * 32 + kq * 8) * 768 + j;
  fp bhh = g ? bhh_p : bhh_c;
  const float* xpg = xp + (size_t)g * 8192 * 768;

  if (tid < 256) { hs[0][j] = 0.f; hs[1][j] = 0.f; }
  if (tid < 128) hsh[0][tid] = 0u;
  else if (tid < 256) hsh[1][tid - 128] = 0u;
  float br = bhh[j], bz = bhh[j + 256], bn = bhh[j + 512];
  int bidx = kq & 1;                   // gate-phase batch (threads < 512)
  int myb = bidx ? b2 : b1;
  int myid = idxv[myb];
  __syncthreads();

  for (int t = 0; t < SS; ++t) {
    // dot phase: packed fp16 h (uint4 = 8 k-values) x packed fp16 weights
    const uint4* h1p = (const uint4*)&hsh[0][kq * 32];
    const uint4* h2p = (const uint4*)&hsh[1][kq * 32];
    float s1r = 0.f, s1z = 0.f, s1n = 0.f;
    float s2r = 0.f, s2z = 0.f, s2n = 0.f;
#pragma unroll
    for (int i = 0; i < 8; ++i) {
      uint4 H1 = h1p[i];
      uint4 H2 = h2p[i];
      const uint4* base = wg + (size_t)i * 768;
      uint4 ur = base[0];
      uint4 uz = base[256];
      uint4 un = base[512];
      s1r = dot2u(H1.x, ur.x, s1r); s1r = dot2u(H1.y, ur.y, s1r);
      s1r = dot2u(H1.z, ur.z, s1r); s1r = dot2u(H1.w, ur.w, s1r);
      s1z = dot2u(H1.x, uz.x, s1z); s1z = dot2u(H1.y, uz.y, s1z);
      s1z = dot2u(H1.z, uz.z, s1z); s1z = dot2u(H1.w, uz.w, s1z);
      s1n = dot2u(H1.x, un.x, s1n); s1n = dot2u(H1.y, un.y, s1n);
      s1n = dot2u(H1.z, un.z, s1n); s1n = dot2u(H1.w, un.w, s1n);
      s2r = dot2u(H2.x, ur.x, s2r); s2r = dot2u(H2.y, ur.y, s2r);
      s2r = dot2u(H2.z, ur.z, s2r); s2r = dot2u(H2.w, ur.w, s2r);
      s2z = dot2u(H2.x, uz.x, s2z); s2z = dot2u(H2.y, uz.y, s2z);
      s2z = dot2u(H2.z, uz.z, s2z); s2z = dot2u(H2.w, uz.w, s2z);
      s2n = dot2u(H2.x, un.x, s2n); s2n = dot2u(H2.y, un.y, s2n);
      s2n = dot2u(H2.z, un.z, s2n); s2n = dot2u(H2.w, un.w, s2n);
    }
    int rb = kq * 6;
    red[rb + 0][j] = s1r; red[rb + 1][j] = s1z; red[rb + 2][j] = s1n;
    red[rb + 3][j] = s2r; red[rb + 4][j] = s2z; red[rb + 5][j] = s2n;
    __syncthreads();                   // partials visible; all hsh reads done

    // gate phase: threads < 512, (bidx = batch-in-pair, j); fp32 state
    if (tid < 512) {
      int bb = bidx * 3;
      float sr = red[bb + 0][j] + red[bb + 6][j] + red[bb + 12][j] + red[bb + 18][j];
      float sz = red[bb + 1][j] + red[bb + 7][j] + red[bb + 13][j] + red[bb + 19][j];
      float sn = red[bb + 2][j] + red[bb + 8][j] + red[bb + 14][j] + red[bb + 20][j];
      const float* xrow = xpg + ((size_t)myb * SS + t) * 768;
      float r = sigm(xrow[j] + sr + br);
      float z = sigm(xrow[j + 256] + sz + bz);
      float n = tanhf(xrow[j + 512] + r * (sn + bn));
      float hnew = (1.f - z) * n + z * hs[bidx][j];
      hs[bidx][j] = hnew;
      if (t == myid) hcat[(size_t)myb * 512 + g * 256 + j] = fmaxf(hnew, 0.f);
    }
    __syncthreads();                   // hs update visible to pack phase

    // pack phase: 4-byte uint stores of fp16 pairs (no sub-dword writes)
    if (tid < 128) {
      unsigned lo16 = __half_as_ushort(__float2half(hs[0][2 * tid]));
      unsigned hi16 = __half_as_ushort(__float2half(hs[0][2 * tid + 1]));
      hsh[0][tid] = lo16 | (hi16 << 16);
    } else if (tid < 256) {
      int p = tid - 128;
      unsigned lo16 = __half_as_ushort(__float2half(hs[1][2 * p]));
      unsigned hi16 = __half_as_ushort(__float2half(hs[1][2 * p + 1]));
      hsh[1][p] = lo16 | (hi16 << 16);
    }
    __syncthreads();                   // hsh visible before next dot phase
  }
}

// ---------------------------------------------------------------------------
// fp32 GEMM for query: C[M,N] = A[M,K] @ W[K,N] + bias
// ---------------------------------------------------------------------------
__global__ __launch_bounds__(256) void gemm_f32(
    const float* __restrict__ A, fp W, fp bias, float* __restrict__ C,
    int M, int N, int K)
{
  int ntiles = N >> 4;
  int mt = blockIdx.x / ntiles, nt = blockIdx.x - mt * ntiles;
  int m0 = mt << 4, n0 = nt << 4;
  int tid = threadIdx.x;
  int ni = tid & 15, mi = tid >> 4;
  __shared__ float As[16][68];
  float acc = 0.f;
  for (int k0 = 0; k0 < K; k0 += 64) {
    __syncthreads();
    for (int i = tid; i < 1024; i += 256) {
      int r = i >> 6, kk = i & 63;
      As[r][kk] = A[(size_t)(m0 + r) * K + k0 + kk];
    }
    __syncthreads();
    const float* wp = W + (size_t)k0 * N + n0 + ni;
#pragma unroll 4
    for (int kk = 0; kk < 64; ++kk)
      acc = fmaf(As[mi][kk], wp[(size_t)kk * N], acc);
  }
  acc += bias[n0 + ni];
  C[(size_t)(m0 + mi) * N + n0 + ni] = acc;
}

// ---------------------------------------------------------------------------
// fused tail per batch row: match/x2/LN (mpnn_att) + bip/masked-linear + mul
// ---------------------------------------------------------------------------
__global__ __launch_bounds__(256) void tail_fused(
    const float* __restrict__ query, const float* __restrict__ embT,
    fp w_out, fp b_out, fp gamma, fp beta,
    fp w_bip, fp b_bip, const float* __restrict__ mw,
    float* __restrict__ out)
{
  int b = blockIdx.x, tid = threadIdx.x;
  __shared__ float q[HH];
  __shared__ float mrow[LBL];
  __shared__ float bips[NSUBS];
  __shared__ float red[256];
  q[tid] = query[(size_t)b * HH + tid];
  __syncthreads();
  if (tid < LBL) {
    float acc = 0.f;
    for (int k = 0; k < HH; ++k) acc += q[k] * embT[(size_t)k * LBL + tid];
    mrow[tid] = sigm(acc);
  }
  for (int s = tid; s < NSUBS; s += 256) {
    float acc = b_bip[s];
    for (int k = 0; k < HH; ++k) acc += q[k] * w_bip[(size_t)k * NSUBS + s];
    bips[s] = acc;
  }
  __syncthreads();
  float x2 = 0.f;
  if (tid < LBL) {
    float acc = b_out[tid] + mrow[tid];
    for (int jj = 0; jj < LBL; ++jj) acc += mrow[jj] * w_out[jj * LBL + tid];
    x2 = acc;
  }
  red[tid] = (tid < LBL) ? x2 : 0.f;
  __syncthreads();
  for (int s = 128; s > 0; s >>= 1) {
    if (tid < s) red[tid] += red[tid + s];
    __syncthreads();
  }
  float mu = red[0] / (float)LBL;
  __syncthreads();
  float dv = (tid < LBL) ? (x2 - mu) : 0.f;
  red[tid] = dv * dv;
  __syncthreads();
  for (int s = 128; s > 0; s >>= 1) {
    if (tid < s) red[tid] += red[tid + s];
    __syncthreads();
  }
  float var = red[0] / (float)LBL;
  if (tid < LBL) {
    float matt = (x2 - mu) * rsqrtf(var + 1e-5f) * gamma[tid] + beta[tid];
    float acc = 0.f;
    for (int s = 0; s < NSUBS; ++s) acc += bips[s] * mw[(size_t)s * LBL + tid];
    out[(size_t)b * LBL + tid] = acc * matt;
  }
}

// ---------------------------------------------------------------------------
extern "C" void kernel_launch(void* const* d_in, const int* in_sizes, int n_in,
                              void* d_out, int out_size, void* d_ws, size_t ws_size,
                              hipStream_t stream)
{
  fp x_c   = (fp)d_in[0];
  fp x_p   = (fp)d_in[1];
  const int* mask = (const int*)d_in[2];
  fp wih_c = (fp)d_in[3];
  fp whh_c = (fp)d_in[4];
  fp bih_c = (fp)d_in[5];
  fp bhh_c = (fp)d_in[6];
  fp wih_p = (fp)d_in[7];
  fp whh_p = (fp)d_in[8];
  fp bih_p = (fp)d_in[9];
  fp bhh_p = (fp)d_in[10];
  fp w_query = (fp)d_in[11];
  fp b_query = (fp)d_in[12];
  fp w_bip = (fp)d_in[13];
  fp b_bip = (fp)d_in[14];
  fp w_masklin = (fp)d_in[15];
  fp ddi = (fp)d_in[16];
  fp embed_fp = (fp)d_in[17];
  const int* fingerprints = (const int*)d_in[18];
  fp adj = (fp)d_in[19];
  const int* seg = (const int*)d_in[20];
  fp w_g0 = (fp)d_in[21];
  fp b_g0 = (fp)d_in[22];
  fp w_g1 = (fp)d_in[23];
  fp b_g1 = (fp)d_in[24];
  fp avg = (fp)d_in[25];
  fp w_out = (fp)d_in[26];
  fp b_out = (fp)d_in[27];
  fp gamma = (fp)d_in[28];
  fp beta = (fp)d_in[29];
  float* out = (float*)d_out;

  char* w = (char*)d_ws;
  size_t off = 0;
  auto alloc = [&](size_t bytes) -> void* {
    void* p = w + off;
    off = (off + bytes + 255) & ~(size_t)255;
    return p;
  };

  float* xp   = (float*)alloc((size_t)2 * 8192 * 768 * 4);    // 50.3 MB
  __half* xhi = (__half*)alloc((size_t)2 * 8192 * 128 * 2);   // 4.2 MB
  __half* xlo = (__half*)alloc((size_t)2 * 8192 * 128 * 2);   // 4.2 MB
  __half* whi = (__half*)alloc((size_t)2 * 768 * 128 * 2);    // 0.4 MB
  __half* wlo = (__half*)alloc((size_t)2 * 768 * 128 * 2);    // 0.4 MB
  uint4* wQ   = (uint4*)alloc((size_t)2 * 32 * 768 * 16);     // 786 KB
  float* mol  = (float*)alloc((size_t)NMOL_N * HH * 4);
  float* embT = (float*)alloc((size_t)HH * LBL * 4);
  float* hcat = (float*)alloc((size_t)BB * 2 * HH * 4);
  float* query = (float*)alloc((size_t)BB * HH * 4);
  float* mw   = (float*)alloc((size_t)NSUBS * LBL * 4);
  int* idxv   = (int*)alloc(256 * 4);
  int* mstart = (int*)alloc((NMOL_N + 1) * 4);

  prep_kernel<<<1190, 256, 0, stream>>>(mask, idxv, seg, mstart, w_masklin,
                                        ddi, mw, whh_c, whh_p, wQ,
                                        x_c, x_p, xhi, xlo,
                                        wih_c, wih_p, whi, wlo);

  xp_mfma<<<dim3(6144, 2), 256, 0, stream>>>(xhi, xlo, whi, wlo,
                                             bih_c, bih_p, xp);

  mpnn_mol<<<NMOL_N, 256, 0, stream>>>(fingerprints, embed_fp, adj, mstart,
                                       w_g0, b_g0, w_g1, b_g1, mol);
  mpnn_emb_k<<<LBL, 256, 0, stream>>>(avg, mol, embT);

  gru_dot4<<<256, 1024, 0, stream>>>(xp, wQ, bhh_c, bhh_p, hcat, idxv);

  gemm_f32<<<256, 256, 0, stream>>>(hcat, w_query, b_query, query, BB, HH, 2 * HH);
  tail_fused<<<BB, 256, 0, stream>>>(query, embT, w_out, b_out, gamma, beta,
                                     w_bip, b_bip, mw, out);
}